// Round 3
// baseline (208.003 us; speedup 1.0000x reference)
//
#include <hip/hip_runtime.h>
#include <cstdint>
#include <cstddef>

typedef float v16f __attribute__((ext_vector_type(16)));
typedef short v8s  __attribute__((ext_vector_type(8)));

#define MFMA32(A,B,C) __builtin_amdgcn_mfma_f32_32x32x16_bf16((A),(B),(C),0,0,0)
#define LIST_CAP 500000u
#define THRU 0.25f

__device__ __forceinline__ unsigned f2bf(float f) {
  unsigned u = __builtin_bit_cast(unsigned, f);
  u += 0x7FFFu + ((u >> 16) & 1u);
  return u >> 16;
}
__device__ __forceinline__ void gload16(const void* g, void* l) {
  __builtin_amdgcn_global_load_lds(
      (const __attribute__((address_space(1))) void*)g,
      (__attribute__((address_space(3))) void*)l, 16, 0, 0);
}

// w = mask ? max(Er*EL, Fr*FL) : 0  (Er,Fr packed bf16 in u)
#define WCOMP(u, ELh, FLh, m) ({                                   \
  float _er = __builtin_bit_cast(float, (u) & 0xFFFF0000u);        \
  float _fr = __builtin_bit_cast(float, (u) << 16);                \
  float _w = fmaxf(_er * (ELh), _fr * (FLh));                      \
  (m) ? _w : 0.f; })

// ---------------------------------------------------------------------------
// prep: h = x @ W^T + b (f32 vector GEMM), bf16-h of x, E/F tables,
//       h stored transposed bf16. Also zeroes the uncertain-list counter.
// ---------------------------------------------------------------------------
__global__ __launch_bounds__(256) void gat_prep(
    const float* __restrict__ nf, const float* __restrict__ Wm,
    const float* __restrict__ bias, const float* __restrict__ aw,
    unsigned short* __restrict__ nfh, unsigned short* __restrict__ ht,
    float* __restrict__ EFl, unsigned* __restrict__ EFu, unsigned* __restrict__ cnt)
{
  __shared__ float xl[32][132];
  const int tid = threadIdx.x;
  const int row = tid & 31, g = tid >> 5;
  const int r0 = blockIdx.x * 32;          // global node row base (0..8191)
  const int b = r0 >> 11, n0 = r0 & 2047;
  const int d0 = g * 16;
  if (blockIdx.x == 0 && tid == 0) cnt[0] = 0;

  float x[16];
  {
    const float* xp = nf + (size_t)(r0 + row) * 128 + d0;
#pragma unroll
    for (int q = 0; q < 4; ++q) {
      float4 v = *(const float4*)(xp + 4 * q);
      x[4*q+0] = v.x; x[4*q+1] = v.y; x[4*q+2] = v.z; x[4*q+3] = v.w;
    }
  }
  {
    unsigned hu[16];
#pragma unroll
    for (int q = 0; q < 16; ++q) { xl[row][d0 + q] = x[q]; hu[q] = f2bf(x[q]); }
    size_t o = (size_t)(r0 + row) * 128 + d0;
    uint4 p0, p1;
    p0.x = hu[0] | (hu[1] << 16);  p0.y = hu[2] | (hu[3] << 16);
    p0.z = hu[4] | (hu[5] << 16);  p0.w = hu[6] | (hu[7] << 16);
    p1.x = hu[8] | (hu[9] << 16);  p1.y = hu[10] | (hu[11] << 16);
    p1.z = hu[12] | (hu[13] << 16); p1.w = hu[14] | (hu[15] << 16);
    *(uint4*)(nfh + o) = p0; *(uint4*)(nfh + o + 8) = p1;
  }
  __syncthreads();

  float acc[16];
  const int ob = g * 16;
#pragma unroll
  for (int o = 0; o < 16; ++o) acc[o] = bias[ob + o];
  for (int dd = 0; dd < 128; dd += 4) {
    float4 xq = *(const float4*)&xl[row][dd];
#pragma unroll
    for (int o = 0; o < 16; ++o) {
      float4 wq = *(const float4*)(Wm + (size_t)(ob + o) * 128 + dd);
      acc[o] = fmaf(xq.x, wq.x, acc[o]);
      acc[o] = fmaf(xq.y, wq.y, acc[o]);
      acc[o] = fmaf(xq.z, wq.z, acc[o]);
      acc[o] = fmaf(xq.w, wq.w, acc[o]);
    }
  }
#pragma unroll
  for (int o = 0; o < 16; ++o)
    ht[((size_t)b * 128 + ob + o) * 2048 + n0 + row] = (unsigned short)f2bf(acc[o]);

  const int hh = g >> 1, cb = (g & 1) * 16;
  float sl = 0.f, sr = 0.f;
#pragma unroll
  for (int o = 0; o < 16; ++o) {
    sl = fmaf(acc[o], aw[hh * 64 + cb + o], sl);
    sr = fmaf(acc[o], aw[hh * 64 + 32 + cb + o], sr);
  }
  sl += __shfl_xor(sl, 32, 64);
  sr += __shfl_xor(sr, 32, 64);
  if (!(g & 1)) {
    const float L2E = 1.4426950408889634f;
    float El = exp2f(sl * L2E), Fl = exp2f(sl * (0.3f * L2E));
    float Er = exp2f(sr * L2E), Fr = exp2f(sr * (0.3f * L2E));
    size_t nn = (size_t)(r0 + row);
    EFl[nn * 8 + hh]     = El;
    EFl[nn * 8 + 4 + hh] = Fl;
    EFu[nn * 4 + hh] = (f2bf(Er) << 16) | f2bf(Fr);
  }
}

// ---------------------------------------------------------------------------
// mask: S_hh = Xh Xh^T sign bits (per (b,i,j)); flag |S|<THR entries into list.
// Per block: 128 i (4 waves) x 64 j. No LDS staging (A-frags direct global,
// L1/L2-hot). One atomicAdd per wave for list append.
// mask layout: u32 mask[b][j>>5][i], bit = j&31.
// ---------------------------------------------------------------------------
__global__ __launch_bounds__(256) void gat_mask(
    const unsigned short* __restrict__ nfh,
    unsigned* __restrict__ mask, unsigned* __restrict__ list,
    unsigned* __restrict__ cnt)
{
  __shared__ unsigned stash[4][256];
  const int tid = threadIdx.x, lane = tid & 63, wv = tid >> 6;
  const int li = lane & 31, hi = lane >> 5;
  const int blk = blockIdx.x;
  const int jb = blk & 31, t = blk >> 5;
  const int ib = t & 15, b = t >> 4;
  const size_t nb = (size_t)b * 2048;
  const int i0 = ib * 128 + wv * 32;
  const int j0 = jb * 64;

  v8s BH[8];
  {
    const size_t ro = (nb + i0 + li) * 128 + hi * 8;
#pragma unroll
    for (int kc = 0; kc < 8; ++kc) BH[kc] = *(const v8s*)(nfh + ro + kc * 16);
  }

  v16f S0, S1;
#pragma unroll
  for (int r = 0; r < 16; ++r) { S0[r] = 0.f; S1[r] = 0.f; }
  {
    const size_t a0 = (nb + j0 + li) * 128 + hi * 8;
#pragma unroll
    for (int kc = 0; kc < 8; ++kc) {
      v8s A0 = *(const v8s*)(nfh + a0 + kc * 16);
      v8s A1 = *(const v8s*)(nfh + a0 + 32 * 128 + kc * 16);
      S0 = MFMA32(A0, BH[kc], S0);
      S1 = MFMA32(A1, BH[kc], S1);
    }
  }

  int wcount = 0;
#pragma unroll
  for (int sub = 0; sub < 2; ++sub) {
    unsigned u = 0;
#pragma unroll
    for (int r = 0; r < 16; ++r) {
      const int jl = (r & 3) + 8 * (r >> 2) + 4 * hi;
      const float s = sub ? S1[r] : S0[r];
      if (s > 0.f) u |= (1u << jl);
      const bool f = fabsf(s) < THRU;
      unsigned long long bal = __ballot(f);
      if (bal) {
        if (f) {
          int pos = wcount + __popcll(bal & ((1ull << lane) - 1ull));
          if (pos < 256)
            stash[wv][pos] = (unsigned)((b << 22) | ((i0 + li) << 11) | (j0 + sub * 32 + jl));
        }
        wcount += (int)__popcll(bal);
      }
    }
    unsigned full = u | (unsigned)__shfl_xor((int)u, 32, 64);
    if (hi == 0)
      mask[(size_t)(b * 64 + jb * 2 + sub) * 2048 + i0 + li] = full;
  }
  if (wcount > 256) wcount = 256;
  unsigned base = 0;
  if (lane == 0 && wcount) base = atomicAdd(cnt, (unsigned)wcount);
  base = (unsigned)__shfl((int)base, 0, 64);
  for (int k = lane; k < wcount; k += 64) {
    unsigned idx = base + k;
    if (idx < LIST_CAP) list[idx] = stash[wv][k];
  }
}

// ---------------------------------------------------------------------------
// fix: exact f64 dot for uncertain entries; rewrite their mask bit.
// ---------------------------------------------------------------------------
__global__ __launch_bounds__(256) void gat_fix(
    const float* __restrict__ nf, const unsigned* __restrict__ list,
    const unsigned* __restrict__ cnt, unsigned* __restrict__ mask)
{
  unsigned n = *cnt; if (n > LIST_CAP) n = LIST_CAP;
  const unsigned t = blockIdx.x * 256 + threadIdx.x;
  if (t >= n) return;
  const unsigned e = list[t];
  const int b = e >> 22, i = (e >> 11) & 2047, j = e & 2047;
  const float* xi = nf + ((size_t)b * 2048 + i) * 128;
  const float* xj = nf + ((size_t)b * 2048 + j) * 128;
  double acc = 0.0;
#pragma unroll 8
  for (int k = 0; k < 128; k += 4) {
    float4 a = *(const float4*)(xi + k);
    float4 c = *(const float4*)(xj + k);
    acc = fma((double)a.x, (double)c.x, acc);
    acc = fma((double)a.y, (double)c.y, acc);
    acc = fma((double)a.z, (double)c.z, acc);
    acc = fma((double)a.w, (double)c.w, acc);
  }
  unsigned* w = &mask[(size_t)(b * 64 + (j >> 5)) * 2048 + i];
  const unsigned bit = 1u << (j & 31);
  if (acc > 0.0) atomicOr(w, bit); else atomicAnd(w, ~bit);
}

// ---------------------------------------------------------------------------
// lean fused attention: per wave 32 i-rows; V+EF staged per 128-j half
// (no per-iter barriers). w from mask bits + E/F tables; PV via MFMA.
// LDS: V 32768 (128 c-rows x 256B, granule-XOR swizzle) | EF 8192.
// ---------------------------------------------------------------------------
#define PVBLK(pw, h)                                                           \
  {                                                                            \
    auto q0 = __builtin_amdgcn_permlane32_swap((int)pw[0], (int)pw[2], false, false); \
    auto q1 = __builtin_amdgcn_permlane32_swap((int)pw[1], (int)pw[3], false, false); \
    auto q2 = __builtin_amdgcn_permlane32_swap((int)pw[4], (int)pw[6], false, false); \
    auto q3 = __builtin_amdgcn_permlane32_swap((int)pw[5], (int)pw[7], false, false); \
    uint4 c0, c1;                                                              \
    c0.x = (unsigned)q0[0]; c0.y = (unsigned)q1[0];                            \
    c0.z = (unsigned)q0[1]; c0.w = (unsigned)q1[1];                            \
    c1.x = (unsigned)q2[0]; c1.y = (unsigned)q3[0];                            \
    c1.z = (unsigned)q2[1]; c1.w = (unsigned)q3[1];                            \
    v8s P0 = __builtin_bit_cast(v8s, c0);                                      \
    v8s P1 = __builtin_bit_cast(v8s, c1);                                      \
    const int cc = (h) * 32 + li;                                              \
    const char* vr = sm + cc * 256;                                            \
    const int cx = cc & 15;                                                    \
    v8s V0 = *(const v8s*)(vr + ((((it2 << 2) + hi) ^ cx) << 4));              \
    v8s V1 = *(const v8s*)(vr + ((((it2 << 2) + 2 + hi) ^ cx) << 4));          \
    acc[h] = MFMA32(P0, V0, acc[h]);                                           \
    acc[h] = MFMA32(P1, V1, acc[h]);                                           \
  }

__global__ __launch_bounds__(256, 2) void gat_attn(
    const unsigned short* __restrict__ ht, const float* __restrict__ EFl,
    const unsigned* __restrict__ EFu, const unsigned* __restrict__ mask,
    float* __restrict__ nump, float* __restrict__ denp, const int CH)
{
  __shared__ __align__(16) char sm[32768 + 8192];
  const int JPC = 2048 / CH, H = JPC >> 7;   // 128-j halves
  const int tid = threadIdx.x, lane = tid & 63, wv = tid >> 6;
  const int li = lane & 31, hi = lane >> 5;

  int blk = blockIdx.x, ig, t2;
  { int x = blk & 7, y = blk >> 3; ig = y & 15; t2 = x * (CH >> 1) + (y >> 4); }
  const int ch = t2 % CH, b = t2 / CH;
  const size_t nb = (size_t)b * 2048;
  const int i0 = ig * 128 + wv * 32;
  const int j0 = ch * JPC;

  float EL[4], FL[4];
  {
    const float* p = EFl + (nb + i0 + li) * 8;
    float4 e = *(const float4*)p;
    float4 f = *(const float4*)(p + 4);
    EL[0] = e.x; EL[1] = e.y; EL[2] = e.z; EL[3] = e.w;
    FL[0] = f.x; FL[1] = f.y; FL[2] = f.z; FL[3] = f.w;
  }

  v16f acc[4];
#pragma unroll
  for (int h = 0; h < 4; ++h)
#pragma unroll
    for (int r = 0; r < 16; ++r) acc[h][r] = 0.f;
  float den[4] = {0.f, 0.f, 0.f, 0.f};

  // EF: all JPC nodes staged once (16B per node)
  for (int q = tid; q < JPC; q += 256)
    gload16((const char*)EFu + (size_t)(nb + j0 + q) * 16, sm + 32768 + q * 16);

  for (int h0 = 0; h0 < H; ++h0) {
    if (h0) __syncthreads();
    {
      const size_t colbase = (size_t)b * 128;
#pragma unroll
      for (int s = 0; s < 8; ++s) {
        const int L = s * 4096 + tid * 16;
        const int c = L >> 8, gs = (L >> 4) & 15;
        const int g = gs ^ (c & 15);
        gload16((const char*)ht + (((colbase + c) * 2048 + (j0 + (h0 << 7))) << 1) + (g << 4),
                sm + L);
      }
    }
    unsigned mw[4];
#pragma unroll
    for (int q = 0; q < 4; ++q)
      mw[q] = mask[(size_t)(b * 64 + (j0 >> 5) + (h0 << 2) + q) * 2048 + i0 + li] >> (hi * 4);
    __syncthreads();

#pragma unroll
    for (int it2 = 0; it2 < 4; ++it2) {
      const char* Eb = sm + 32768 + ((h0 << 2) + it2) * 512;
      const unsigned mh = mw[it2];
#pragma unroll
      for (int hp = 0; hp < 2; ++hp) {
        unsigned pA[8], pB[8];
#pragma unroll
        for (int rp = 0; rp < 8; ++rp) {
          const int r0 = 2 * rp;
          const int jl0c = (r0 & 3) + 8 * (r0 >> 2);
          const int jb0 = (jl0c + 4 * hi) * 16 + hp * 8;
          uint2 e0 = *(const uint2*)(Eb + jb0);
          uint2 e1 = *(const uint2*)(Eb + jb0 + 16);
          const bool m0 = (mh >> jl0c) & 1;
          const bool m1 = (mh >> (jl0c + 1)) & 1;
          float w00 = WCOMP(e0.x, EL[2*hp],   FL[2*hp],   m0);
          float w01 = WCOMP(e0.y, EL[2*hp+1], FL[2*hp+1], m0);
          float w10 = WCOMP(e1.x, EL[2*hp],   FL[2*hp],   m1);
          float w11 = WCOMP(e1.y, EL[2*hp+1], FL[2*hp+1], m1);
          den[2*hp]   += w00 + w10;
          den[2*hp+1] += w01 + w11;
          asm("v_cvt_pk_bf16_f32 %0, %1, %2" : "=v"(pA[rp]) : "v"(w00), "v"(w10));
          asm("v_cvt_pk_bf16_f32 %0, %1, %2" : "=v"(pB[rp]) : "v"(w01), "v"(w11));
        }
        PVBLK(pA, 2 * hp)
        PVBLK(pB, 2 * hp + 1)
      }
    }
  }

#pragma unroll
  for (int h = 0; h < 4; ++h) den[h] += __shfl_xor(den[h], 32, 64);

  const size_t obase = ((size_t)b * CH + ch) * 2048 + i0;
#pragma unroll
  for (int h = 0; h < 4; ++h) {
#pragma unroll
    for (int r = 0; r < 16; ++r) {
      const int il = (r & 3) + 8 * (r >> 2) + 4 * hi;
      nump[(obase + il) * 128 + h * 32 + li] = acc[h][r];
    }
  }
  if (lane < 32) {
    float4 dv;
    dv.x = den[0]; dv.y = den[1]; dv.z = den[2]; dv.w = den[3];
    *(float4*)(denp + (obase + li) * 4) = dv;
  }
}

// ---------------------------------------------------------------------------
// reduce: out = (sum_ch num) / (sum_ch den)
// ---------------------------------------------------------------------------
__global__ __launch_bounds__(256) void gat_reduce(
    const float* __restrict__ nump, const float* __restrict__ denp,
    float* __restrict__ out, const int CH)
{
  const int idx = blockIdx.x * 256 + threadIdx.x;
  const int b = idx >> 18;
  const int rem = idx & 262143;
  const int n = rem >> 7;
  const int col = rem & 127;
  const int h = col >> 5;
  float s = 0.f, d = 0.f;
  for (int ch = 0; ch < CH; ++ch) {
    s += nump[(((size_t)b * CH + ch) * 2048 + n) * 128 + col];
    d += denp[(((size_t)b * CH + ch) * 2048 + n) * 4 + h];
  }
  out[idx] = s / d;
}

// ---------------------------------------------------------------------------
extern "C" void kernel_launch(void* const* d_in, const int* in_sizes, int n_in,
                              void* d_out, int out_size, void* d_ws, size_t ws_size,
                              hipStream_t stream) {
  const float* nf   = (const float*)d_in[0];
  const float* Wm   = (const float*)d_in[1];
  const float* bias = (const float*)d_in[2];
  const float* aw   = (const float*)d_in[3];
  float* out = (float*)d_out;
  char* ws = (char*)d_ws;

  // layout (bytes)
  unsigned short* nfh = (unsigned short*)(ws);             // 2,097,152
  unsigned short* ht  = (unsigned short*)(ws + 2097152);   // 2,097,152
  float*    EFl  = (float*)(ws + 4194304);                 //   262,144
  unsigned* EFu  = (unsigned*)(ws + 4456448);              //   131,072
  unsigned* mask = (unsigned*)(ws + 4587520);              // 2,097,152
  unsigned* list = (unsigned*)(ws + 6684672);              // 2,000,000
  unsigned* cnt  = (unsigned*)(ws + 8684672);              //       256
  const size_t o_den = 8684928;

  // need(CH) = 8684928 + CH*(4194304 + 131072)
  int CH = 8;
  if (ws_size >= 8684928ull + 16ull * 4325376ull) CH = 16;
  else if (ws_size < 8684928ull + 8ull * 4325376ull) CH = 4;

  float* denp = (float*)(ws + o_den);
  float* nump = (float*)(ws + o_den + (size_t)CH * 131072);

  gat_prep<<<256, 256, 0, stream>>>(nf, Wm, bias, aw, nfh, ht, EFl, EFu, cnt);
  gat_mask<<<2048, 256, 0, stream>>>(nfh, mask, list, cnt);
  gat_fix<<<(LIST_CAP + 255) / 256, 256, 0, stream>>>(nf, list, cnt, mask);
  gat_attn<<<64 * CH, 256, 0, stream>>>(ht, EFl, EFu, mask, nump, denp, CH);
  gat_reduce<<<4096, 256, 0, stream>>>(nump, denp, out, CH);
}

// Round 4
// 116.495 us; speedup vs baseline: 1.7855x; 1.7855x over previous
//
#include <hip/hip_runtime.h>
#include <cstdint>
#include <cstddef>

typedef float v16f __attribute__((ext_vector_type(16)));
typedef short v8s  __attribute__((ext_vector_type(8)));

#define MFMA32(A,B,C) __builtin_amdgcn_mfma_f32_32x32x16_bf16((A),(B),(C),0,0,0)
#define THRU 1e-3f
#define SEG 16

__device__ __forceinline__ unsigned f2bf(float f) {
  unsigned u = __builtin_bit_cast(unsigned, f);
  u += 0x7FFFu + ((u >> 16) & 1u);
  return u >> 16;
}
__device__ __forceinline__ float bf2f(unsigned us) {
  return __builtin_bit_cast(float, us << 16);
}
__device__ __forceinline__ void gload16(const void* g, void* l) {
  __builtin_amdgcn_global_load_lds(
      (const __attribute__((address_space(1))) void*)g,
      (__attribute__((address_space(3))) void*)l, 16, 0, 0);
}

// w = mask ? max(Er*EL, Fr*FL) : 0  (Er,Fr packed bf16 in u)
#define WCOMP(u, ELh, FLh, m) ({                                   \
  float _er = __builtin_bit_cast(float, (u) & 0xFFFF0000u);        \
  float _fr = __builtin_bit_cast(float, (u) << 16);                \
  float _w = fmaxf(_er * (ELh), _fr * (FLh));                      \
  (m) ? _w : 0.f; })

// ---------------------------------------------------------------------------
// prep: h = x @ W^T + b (f32 vector GEMM); bf16 h/m splits of x; E/F tables;
//       h stored transposed bf16.
// ---------------------------------------------------------------------------
__global__ __launch_bounds__(256) void gat_prep(
    const float* __restrict__ nf, const float* __restrict__ Wm,
    const float* __restrict__ bias, const float* __restrict__ aw,
    unsigned short* __restrict__ nfh, unsigned short* __restrict__ nfm,
    unsigned short* __restrict__ ht,
    float* __restrict__ EFl, unsigned* __restrict__ EFu)
{
  __shared__ float xl[32][132];
  const int tid = threadIdx.x;
  const int row = tid & 31, g = tid >> 5;
  const int r0 = blockIdx.x * 32;          // global node row base (0..8191)
  const int b = r0 >> 11, n0 = r0 & 2047;
  const int d0 = g * 16;

  float x[16];
  {
    const float* xp = nf + (size_t)(r0 + row) * 128 + d0;
#pragma unroll
    for (int q = 0; q < 4; ++q) {
      float4 v = *(const float4*)(xp + 4 * q);
      x[4*q+0] = v.x; x[4*q+1] = v.y; x[4*q+2] = v.z; x[4*q+3] = v.w;
    }
  }
  {
    unsigned hu[16], mu[16];
#pragma unroll
    for (int q = 0; q < 16; ++q) {
      xl[row][d0 + q] = x[q];
      unsigned hb = f2bf(x[q]); float hf = bf2f(hb);
      unsigned mb = f2bf(x[q] - hf);
      hu[q] = hb; mu[q] = mb;
    }
    size_t o = (size_t)(r0 + row) * 128 + d0;
    uint4 p0, p1;
    p0.x = hu[0] | (hu[1] << 16);  p0.y = hu[2] | (hu[3] << 16);
    p0.z = hu[4] | (hu[5] << 16);  p0.w = hu[6] | (hu[7] << 16);
    p1.x = hu[8] | (hu[9] << 16);  p1.y = hu[10] | (hu[11] << 16);
    p1.z = hu[12] | (hu[13] << 16); p1.w = hu[14] | (hu[15] << 16);
    *(uint4*)(nfh + o) = p0; *(uint4*)(nfh + o + 8) = p1;
    p0.x = mu[0] | (mu[1] << 16);  p0.y = mu[2] | (mu[3] << 16);
    p0.z = mu[4] | (mu[5] << 16);  p0.w = mu[6] | (mu[7] << 16);
    p1.x = mu[8] | (mu[9] << 16);  p1.y = mu[10] | (mu[11] << 16);
    p1.z = mu[12] | (mu[13] << 16); p1.w = mu[14] | (mu[15] << 16);
    *(uint4*)(nfm + o) = p0; *(uint4*)(nfm + o + 8) = p1;
  }
  __syncthreads();

  float acc[16];
  const int ob = g * 16;
#pragma unroll
  for (int o = 0; o < 16; ++o) acc[o] = bias[ob + o];
  for (int dd = 0; dd < 128; dd += 4) {
    float4 xq = *(const float4*)&xl[row][dd];
#pragma unroll
    for (int o = 0; o < 16; ++o) {
      float4 wq = *(const float4*)(Wm + (size_t)(ob + o) * 128 + dd);
      acc[o] = fmaf(xq.x, wq.x, acc[o]);
      acc[o] = fmaf(xq.y, wq.y, acc[o]);
      acc[o] = fmaf(xq.z, wq.z, acc[o]);
      acc[o] = fmaf(xq.w, wq.w, acc[o]);
    }
  }
#pragma unroll
  for (int o = 0; o < 16; ++o)
    ht[((size_t)b * 128 + ob + o) * 2048 + n0 + row] = (unsigned short)f2bf(acc[o]);

  const int hh = g >> 1, cb = (g & 1) * 16;
  float sl = 0.f, sr = 0.f;
#pragma unroll
  for (int o = 0; o < 16; ++o) {
    sl = fmaf(acc[o], aw[hh * 64 + cb + o], sl);
    sr = fmaf(acc[o], aw[hh * 64 + 32 + cb + o], sr);
  }
  sl += __shfl_xor(sl, 32, 64);
  sr += __shfl_xor(sr, 32, 64);
  if (!(g & 1)) {
    const float L2E = 1.4426950408889634f;
    float El = exp2f(sl * L2E), Fl = exp2f(sl * (0.3f * L2E));
    float Er = exp2f(sr * L2E), Fr = exp2f(sr * (0.3f * L2E));
    size_t nn = (size_t)(r0 + row);
    EFl[nn * 8 + hh]     = El;
    EFl[nn * 8 + 4 + hh] = Fl;
    EFu[nn * 4 + hh] = (f2bf(Er) << 16) | f2bf(Fr);
  }
}

// ---------------------------------------------------------------------------
// mask: S = 3-pass split-bf16 (hh+hm+mh), error sigma ~3.7e-5. Sign bits to
// mask words; |S|<1e-3 entries appended to THIS WAVE's private list segment
// (plain stores, ballot prefix — ZERO atomics).
// mask layout: u32 mask[b][j>>5][i], bit = j&31.
// ---------------------------------------------------------------------------
__global__ __launch_bounds__(256) void gat_mask(
    const unsigned short* __restrict__ nfh, const unsigned short* __restrict__ nfm,
    unsigned* __restrict__ mask, unsigned* __restrict__ list,
    unsigned* __restrict__ lcnt)
{
  const int tid = threadIdx.x, lane = tid & 63, wv = tid >> 6;
  const int li = lane & 31, hi = lane >> 5;
  const int blk = blockIdx.x;
  const int jb = blk & 31, t = blk >> 5;
  const int ib = t & 15, b = t >> 4;
  const size_t nb = (size_t)b * 2048;
  const int i0 = ib * 128 + wv * 32;
  const int j0 = jb * 64;
  const int wid = blk * 4 + wv;

  v8s BH[8], BM[8];
  {
    const size_t ro = (nb + i0 + li) * 128 + hi * 8;
#pragma unroll
    for (int kc = 0; kc < 8; ++kc) {
      BH[kc] = *(const v8s*)(nfh + ro + kc * 16);
      BM[kc] = *(const v8s*)(nfm + ro + kc * 16);
    }
  }

  v16f S0, S1;
#pragma unroll
  for (int r = 0; r < 16; ++r) { S0[r] = 0.f; S1[r] = 0.f; }
  {
    const size_t a0 = (nb + j0 + li) * 128 + hi * 8;
#pragma unroll
    for (int kc = 0; kc < 8; ++kc) {
      v8s A0h = *(const v8s*)(nfh + a0 + kc * 16);
      v8s A1h = *(const v8s*)(nfh + a0 + 32 * 128 + kc * 16);
      v8s A0m = *(const v8s*)(nfm + a0 + kc * 16);
      v8s A1m = *(const v8s*)(nfm + a0 + 32 * 128 + kc * 16);
      S0 = MFMA32(A0h, BH[kc], S0);
      S1 = MFMA32(A1h, BH[kc], S1);
      S0 = MFMA32(A0h, BM[kc], S0);
      S1 = MFMA32(A1h, BM[kc], S1);
      S0 = MFMA32(A0m, BH[kc], S0);
      S1 = MFMA32(A1m, BH[kc], S1);
    }
  }

  int wcount = 0;
#pragma unroll
  for (int sub = 0; sub < 2; ++sub) {
    unsigned u = 0;
#pragma unroll
    for (int r = 0; r < 16; ++r) {
      const int jl = (r & 3) + 8 * (r >> 2) + 4 * hi;
      const float s = sub ? S1[r] : S0[r];
      if (s > 0.f) u |= (1u << jl);
      const bool f = fabsf(s) < THRU;
      unsigned long long bal = __ballot(f);
      if (bal) {
        if (f) {
          int pos = wcount + (int)__popcll(bal & ((1ull << lane) - 1ull));
          if (pos < SEG)
            list[wid * SEG + pos] =
                (unsigned)((b << 22) | ((i0 + li) << 11) | (j0 + sub * 32 + jl));
        }
        wcount += (int)__popcll(bal);
      }
    }
    unsigned full = u | (unsigned)__shfl_xor((int)u, 32, 64);
    if (hi == 0)
      mask[(size_t)(b * 64 + jb * 2 + sub) * 2048 + i0 + li] = full;
  }
  if (lane == 0) lcnt[wid] = (unsigned)(wcount > SEG ? SEG : wcount);
}

// ---------------------------------------------------------------------------
// fix: exact f64 dot for uncertain entries (~1K total); rewrite mask bits.
// ---------------------------------------------------------------------------
__global__ __launch_bounds__(256) void gat_fix(
    const float* __restrict__ nf, const unsigned* __restrict__ list,
    const unsigned* __restrict__ lcnt, unsigned* __restrict__ mask)
{
  const unsigned t = blockIdx.x * 256 + threadIdx.x;   // 8192*SEG threads
  const unsigned seg = t >> 4, slot = t & (SEG - 1);
  if (slot >= lcnt[seg]) return;
  const unsigned e = list[t];
  const int b = e >> 22, i = (e >> 11) & 2047, j = e & 2047;
  const float* xi = nf + ((size_t)b * 2048 + i) * 128;
  const float* xj = nf + ((size_t)b * 2048 + j) * 128;
  double acc = 0.0;
#pragma unroll 8
  for (int k = 0; k < 128; k += 4) {
    float4 a = *(const float4*)(xi + k);
    float4 c = *(const float4*)(xj + k);
    acc = fma((double)a.x, (double)c.x, acc);
    acc = fma((double)a.y, (double)c.y, acc);
    acc = fma((double)a.z, (double)c.z, acc);
    acc = fma((double)a.w, (double)c.w, acc);
  }
  unsigned* w = &mask[(size_t)(b * 64 + (j >> 5)) * 2048 + i];
  const unsigned bit = 1u << (j & 31);
  if (acc > 0.0) atomicOr(w, bit); else atomicAnd(w, ~bit);
}

// ---------------------------------------------------------------------------
// lean fused attention: per wave 32 i-rows; V+EF staged per 128-j half
// (no per-iter barriers). w from mask bits + E/F tables; PV via MFMA.
// LDS: V 32768 (128 c-rows x 256B, granule-XOR swizzle) | EF 8192.
// ---------------------------------------------------------------------------
#define PVBLK(pw, h)                                                           \
  {                                                                            \
    auto q0 = __builtin_amdgcn_permlane32_swap((int)pw[0], (int)pw[2], false, false); \
    auto q1 = __builtin_amdgcn_permlane32_swap((int)pw[1], (int)pw[3], false, false); \
    auto q2 = __builtin_amdgcn_permlane32_swap((int)pw[4], (int)pw[6], false, false); \
    auto q3 = __builtin_amdgcn_permlane32_swap((int)pw[5], (int)pw[7], false, false); \
    uint4 c0, c1;                                                              \
    c0.x = (unsigned)q0[0]; c0.y = (unsigned)q1[0];                            \
    c0.z = (unsigned)q0[1]; c0.w = (unsigned)q1[1];                            \
    c1.x = (unsigned)q2[0]; c1.y = (unsigned)q3[0];                            \
    c1.z = (unsigned)q2[1]; c1.w = (unsigned)q3[1];                            \
    v8s P0 = __builtin_bit_cast(v8s, c0);                                      \
    v8s P1 = __builtin_bit_cast(v8s, c1);                                      \
    const int cc = (h) * 32 + li;                                              \
    const char* vr = sm + cc * 256;                                            \
    const int cx = cc & 15;                                                    \
    v8s V0 = *(const v8s*)(vr + ((((it2 << 2) + hi) ^ cx) << 4));              \
    v8s V1 = *(const v8s*)(vr + ((((it2 << 2) + 2 + hi) ^ cx) << 4));          \
    acc[h] = MFMA32(P0, V0, acc[h]);                                           \
    acc[h] = MFMA32(P1, V1, acc[h]);                                           \
  }

__global__ __launch_bounds__(256, 2) void gat_attn(
    const unsigned short* __restrict__ ht, const float* __restrict__ EFl,
    const unsigned* __restrict__ EFu, const unsigned* __restrict__ mask,
    float* __restrict__ nump, float* __restrict__ denp, const int CH)
{
  __shared__ __align__(16) char sm[32768 + 8192];
  const int JPC = 2048 / CH, H = JPC >> 7;   // 128-j halves
  const int tid = threadIdx.x, lane = tid & 63, wv = tid >> 6;
  const int li = lane & 31, hi = lane >> 5;

  int blk = blockIdx.x, ig, t2;
  { int x = blk & 7, y = blk >> 3; ig = y & 15; t2 = x * (CH >> 1) + (y >> 4); }
  const int ch = t2 % CH, b = t2 / CH;
  const size_t nb = (size_t)b * 2048;
  const int i0 = ig * 128 + wv * 32;
  const int j0 = ch * JPC;

  float EL[4], FL[4];
  {
    const float* p = EFl + (nb + i0 + li) * 8;
    float4 e = *(const float4*)p;
    float4 f = *(const float4*)(p + 4);
    EL[0] = e.x; EL[1] = e.y; EL[2] = e.z; EL[3] = e.w;
    FL[0] = f.x; FL[1] = f.y; FL[2] = f.z; FL[3] = f.w;
  }

  v16f acc[4];
#pragma unroll
  for (int h = 0; h < 4; ++h)
#pragma unroll
    for (int r = 0; r < 16; ++r) acc[h][r] = 0.f;
  float den[4] = {0.f, 0.f, 0.f, 0.f};

  // EF: all JPC nodes staged once (16B per node)
  for (int q = tid; q < JPC; q += 256)
    gload16((const char*)EFu + (size_t)(nb + j0 + q) * 16, sm + 32768 + q * 16);

  for (int h0 = 0; h0 < H; ++h0) {
    if (h0) __syncthreads();
    {
      const size_t colbase = (size_t)b * 128;
#pragma unroll
      for (int s = 0; s < 8; ++s) {
        const int L = s * 4096 + tid * 16;
        const int c = L >> 8, gs = (L >> 4) & 15;
        const int g = gs ^ (c & 15);
        gload16((const char*)ht + (((colbase + c) * 2048 + (j0 + (h0 << 7))) << 1) + (g << 4),
                sm + L);
      }
    }
    unsigned mw[4];
#pragma unroll
    for (int q = 0; q < 4; ++q)
      mw[q] = mask[(size_t)(b * 64 + (j0 >> 5) + (h0 << 2) + q) * 2048 + i0 + li] >> (hi * 4);
    __syncthreads();

#pragma unroll
    for (int it2 = 0; it2 < 4; ++it2) {
      const char* Eb = sm + 32768 + ((h0 << 2) + it2) * 512;
      const unsigned mh = mw[it2];
#pragma unroll
      for (int hp = 0; hp < 2; ++hp) {
        unsigned pA[8], pB[8];
#pragma unroll
        for (int rp = 0; rp < 8; ++rp) {
          const int r0 = 2 * rp;
          const int jl0c = (r0 & 3) + 8 * (r0 >> 2);
          const int jb0 = (jl0c + 4 * hi) * 16 + hp * 8;
          uint2 e0 = *(const uint2*)(Eb + jb0);
          uint2 e1 = *(const uint2*)(Eb + jb0 + 16);
          const bool m0 = (mh >> jl0c) & 1;
          const bool m1 = (mh >> (jl0c + 1)) & 1;
          float w00 = WCOMP(e0.x, EL[2*hp],   FL[2*hp],   m0);
          float w01 = WCOMP(e0.y, EL[2*hp+1], FL[2*hp+1], m0);
          float w10 = WCOMP(e1.x, EL[2*hp],   FL[2*hp],   m1);
          float w11 = WCOMP(e1.y, EL[2*hp+1], FL[2*hp+1], m1);
          den[2*hp]   += w00 + w10;
          den[2*hp+1] += w01 + w11;
          asm("v_cvt_pk_bf16_f32 %0, %1, %2" : "=v"(pA[rp]) : "v"(w00), "v"(w10));
          asm("v_cvt_pk_bf16_f32 %0, %1, %2" : "=v"(pB[rp]) : "v"(w01), "v"(w11));
        }
        PVBLK(pA, 2 * hp)
        PVBLK(pB, 2 * hp + 1)
      }
    }
  }

#pragma unroll
  for (int h = 0; h < 4; ++h) den[h] += __shfl_xor(den[h], 32, 64);

  const size_t obase = ((size_t)b * CH + ch) * 2048 + i0;
#pragma unroll
  for (int h = 0; h < 4; ++h) {
#pragma unroll
    for (int r = 0; r < 16; ++r) {
      const int il = (r & 3) + 8 * (r >> 2) + 4 * hi;
      nump[(obase + il) * 128 + h * 32 + li] = acc[h][r];
    }
  }
  if (lane < 32) {
    float4 dv;
    dv.x = den[0]; dv.y = den[1]; dv.z = den[2]; dv.w = den[3];
    *(float4*)(denp + (obase + li) * 4) = dv;
  }
}

// ---------------------------------------------------------------------------
// reduce: out = (sum_ch num) / (sum_ch den)
// ---------------------------------------------------------------------------
__global__ __launch_bounds__(256) void gat_reduce(
    const float* __restrict__ nump, const float* __restrict__ denp,
    float* __restrict__ out, const int CH)
{
  const int idx = blockIdx.x * 256 + threadIdx.x;
  const int b = idx >> 18;
  const int rem = idx & 262143;
  const int n = rem >> 7;
  const int col = rem & 127;
  const int h = col >> 5;
  float s = 0.f, d = 0.f;
  for (int ch = 0; ch < CH; ++ch) {
    s += nump[(((size_t)b * CH + ch) * 2048 + n) * 128 + col];
    d += denp[(((size_t)b * CH + ch) * 2048 + n) * 4 + h];
  }
  out[idx] = s / d;
}

// ---------------------------------------------------------------------------
extern "C" void kernel_launch(void* const* d_in, const int* in_sizes, int n_in,
                              void* d_out, int out_size, void* d_ws, size_t ws_size,
                              hipStream_t stream) {
  const float* nf   = (const float*)d_in[0];
  const float* Wm   = (const float*)d_in[1];
  const float* bias = (const float*)d_in[2];
  const float* aw   = (const float*)d_in[3];
  float* out = (float*)d_out;
  char* ws = (char*)d_ws;

  // layout (bytes)
  unsigned short* nfh = (unsigned short*)(ws);             // 2,097,152
  unsigned short* nfm = (unsigned short*)(ws + 2097152);   // 2,097,152
  unsigned short* ht  = (unsigned short*)(ws + 4194304);   // 2,097,152
  float*    EFl  = (float*)(ws + 6291456);                 //   262,144
  unsigned* EFu  = (unsigned*)(ws + 6553600);              //   131,072
  unsigned* mask = (unsigned*)(ws + 6684672);              // 2,097,152
  unsigned* list = (unsigned*)(ws + 8781824);              //   524,288 (8192*16*4)
  unsigned* lcnt = (unsigned*)(ws + 9306112);              //    32,768
  const size_t o_den = 9338880;

  // need(CH) = o_den + CH*(4194304 + 131072)
  int CH = 8;
  if (ws_size >= o_den + 16ull * 4325376ull) CH = 16;
  else if (ws_size < o_den + 8ull * 4325376ull) CH = 4;

  float* denp = (float*)(ws + o_den);
  float* nump = (float*)(ws + o_den + (size_t)CH * 131072);

  gat_prep<<<256, 256, 0, stream>>>(nf, Wm, bias, aw, nfh, nfm, ht, EFl, EFu);
  gat_mask<<<2048, 256, 0, stream>>>(nfh, nfm, mask, list, lcnt);
  gat_fix<<<512, 256, 0, stream>>>(nf, list, lcnt, mask);
  gat_attn<<<64 * CH, 256, 0, stream>>>(ht, EFl, EFu, mask, nump, denp, CH);
  gat_reduce<<<4096, 256, 0, stream>>>(nump, denp, out, CH);
}